// Round 6
// baseline (579.935 us; speedup 1.0000x reference)
//
#include <hip/hip_runtime.h>
#include <hip/hip_bf16.h>

// B=2, S=2048, D=2048, H=16, HD=128, causal MHA with 4 linear projections.
// weights cvt (one small launch) -> batched QKV GEMM reading fp32 activations
// directly (2-tile-lookahead reg-staged cvt into LDS A-ring; B via gl_lds16
// 3-ring with counted vmcnt(10); ks-split 2-phase, XCD-clustered blocks,
// V transposed per head) -> flash attn (transposed scores, per-lane softmax
// rows, lane-partial l_i, dbuf K/V, XCD-grouped heads) -> out-proj GEMM.

#define LOG2E 1.44269504088896340736f

typedef __attribute__((ext_vector_type(8))) short short8;    // 8 x bf16
typedef __attribute__((ext_vector_type(4))) short short4b;   // 4 x bf16
typedef __attribute__((ext_vector_type(4))) float floatx4;   // MFMA acc

__device__ __forceinline__ short f2bf(float f) {
  unsigned int u = __builtin_bit_cast(unsigned int, f);
  u += 0x7FFFu + ((u >> 16) & 1u);  // RNE
  return (short)(u >> 16);
}

__device__ __forceinline__ short8 cvt8(float4 f0, float4 f1) {
  return (short8){f2bf(f0.x), f2bf(f0.y), f2bf(f0.z), f2bf(f0.w),
                  f2bf(f1.x), f2bf(f1.y), f2bf(f1.z), f2bf(f1.w)};
}

__device__ __forceinline__ short4b pack4bf(float a, float b, float c, float d) {
  __hip_bfloat162 lo = __float22bfloat162_rn(float2{a, b});
  __hip_bfloat162 hi = __float22bfloat162_rn(float2{c, d});
  short4b r;
  r[0] = __builtin_bit_cast(short, lo.x); r[1] = __builtin_bit_cast(short, lo.y);
  r[2] = __builtin_bit_cast(short, hi.x); r[3] = __builtin_bit_cast(short, hi.y);
  return r;
}

__device__ __forceinline__ void gl_lds16(const void* g, void* l) {
  __builtin_amdgcn_global_load_lds(
      (const __attribute__((address_space(1))) unsigned int*)g,
      (__attribute__((address_space(3))) unsigned int*)l, 16, 0, 0);
}

// ---------------- fp32 -> bf16 conversion (weights; 4 arrays) ---------------
__global__ __launch_bounds__(256) void cvt_k(
    const float* __restrict__ s0, const float* __restrict__ s1,
    const float* __restrict__ s2, const float* __restrict__ s3,
    unsigned short* __restrict__ d0, unsigned short* __restrict__ d1,
    unsigned short* __restrict__ d2, unsigned short* __restrict__ d3, int n)
{
  const float* s; unsigned short* d;
  switch (blockIdx.y) {
    case 0: s = s0; d = d0; break;
    case 1: s = s1; d = d1; break;
    case 2: s = s2; d = d2; break;
    default: s = s3; d = d3; break;
  }
  const int i = (blockIdx.x * 256 + threadIdx.x) * 8;
  if (i >= n) return;
  float4 a = *(const float4*)(s + i);
  float4 b = *(const float4*)(s + i + 4);
  *(short8*)(d + i) = cvt8(a, b);
}

// ============ shared GEMM body (ks-split 2-phase, bf16 A) as a macro =========
// BM=256, BN=128, BK=64, 512 thr = 8 waves (4M x 2N). LDS 3-ring (A+B).
// Per K-tile 2 phases: 8 balanced ds_read_b128 + 3 gl_lds16 + 16 independent
// MFMA; end-of-tile vmcnt(6) publishes t+1 (t+2 in flight).
#define GEMM_CORE(A_, Bt_)                                                     \
  const unsigned short* gA[4]; int lAo[4];                                     \
  const unsigned short* gB[2]; int lBo[2];                                     \
  _Pragma("unroll")                                                            \
  for (int j = 0; j < 4; ++j) {                                                \
    const int pa = ((j >> 1) * 16 + wave * 2 + (j & 1)) * 64 + lane;           \
    const int r = pa >> 3, cp = pa & 7, cs = cp ^ (r & 7);                     \
    gA[j]  = A_ + (bm + r) * (long)K + cs * 8;                                 \
    lAo[j] = pa * 8;                                                           \
  }                                                                            \
  _Pragma("unroll")                                                            \
  for (int j = 0; j < 2; ++j) {                                                \
    const int pb = (wave * 2 + j) * 64 + lane;                                 \
    const int r = pb >> 3, cp = pb & 7, cs = cp ^ (r & 7);                     \
    gB[j]  = Bt_ + (bn + r) * (long)K + cs * 8;                                \
    lBo[j] = pb * 8;                                                           \
  }                                                                            \
  floatx4 acc[4][4];                                                           \
  _Pragma("unroll")                                                            \
  for (int i = 0; i < 4; ++i)                                                  \
    _Pragma("unroll")                                                          \
    for (int j = 0; j < 4; ++j) acc[i][j] = (floatx4){0.f, 0.f, 0.f, 0.f};     \
  const int NT = K >> 6;                                                       \
  _Pragma("unroll")                                                            \
  for (int j = 0; j < 4; ++j) gl_lds16(gA[j], &As[0][lAo[j]]);                 \
  _Pragma("unroll")                                                            \
  for (int j = 0; j < 2; ++j) gl_lds16(gB[j], &Bs[0][lBo[j]]);                 \
  if (NT > 1) {                                                                \
    _Pragma("unroll")                                                          \
    for (int j = 0; j < 4; ++j) gl_lds16(gA[j] + 64, &As[1][lAo[j]]);          \
    _Pragma("unroll")                                                          \
    for (int j = 0; j < 2; ++j) gl_lds16(gB[j] + 64, &Bs[1][lBo[j]]);          \
    asm volatile("s_waitcnt vmcnt(6)" ::: "memory");                           \
  } else {                                                                     \
    asm volatile("s_waitcnt vmcnt(0)" ::: "memory");                           \
  }                                                                            \
  __builtin_amdgcn_s_barrier();                                                \
  int cur3 = 0;                                                                \
  for (int t = 0; t < NT; ++t) {                                               \
    int nx2 = cur3 + 2; if (nx2 >= 3) nx2 -= 3;                                \
    const long kk2 = (long)(t + 2) * 64;                                       \
    const bool st2 = (t + 2) < NT;                                             \
    const bool st1 = (t + 1) < NT;                                             \
    const unsigned short* Ab = As[cur3];                                       \
    const unsigned short* Bb = Bs[cur3];                                       \
    /* ---- phase 0 (ks=0) ---- */                                             \
    short8 af0[4], bf0[4];                                                     \
    _Pragma("unroll")                                                          \
    for (int mt = 0; mt < 4; ++mt)                                             \
      af0[mt] = *(const short8*)&Ab[(wm * 64 + mt * 16 + l16) * 64 +           \
                                    ((quad ^ lx7) * 8)];                       \
    _Pragma("unroll")                                                          \
    for (int nt = 0; nt < 4; ++nt)                                             \
      bf0[nt] = *(const short8*)&Bb[(wn * 64 + nt * 16 + l16) * 64 +           \
                                    ((quad ^ lx7) * 8)];                       \
    if (st2) { gl_lds16(gA[0] + kk2, &As[nx2][lAo[0]]);                        \
               gl_lds16(gA[1] + kk2, &As[nx2][lAo[1]]);                        \
               gl_lds16(gA[2] + kk2, &As[nx2][lAo[2]]); }                      \
    __builtin_amdgcn_s_barrier();                                              \
    asm volatile("s_waitcnt lgkmcnt(0)");                                      \
    __builtin_amdgcn_s_setprio(1);                                             \
    _Pragma("unroll")                                                          \
    for (int nt = 0; nt < 4; ++nt)                                             \
      _Pragma("unroll")                                                        \
      for (int mt = 0; mt < 4; ++mt)                                           \
        acc[mt][nt] = __builtin_amdgcn_mfma_f32_16x16x32_bf16(                 \
            af0[mt], bf0[nt], acc[mt][nt], 0, 0, 0);                           \
    __builtin_amdgcn_s_setprio(0);                                             \
    __builtin_amdgcn_s_barrier();                                              \
    /* ---- phase 1 (ks=1) ---- */                                             \
    short8 af1[4], bf1[4];                                                     \
    _Pragma("unroll")                                                          \
    for (int mt = 0; mt < 4; ++mt)                                             \
      af1[mt] = *(const short8*)&Ab[(wm * 64 + mt * 16 + l16) * 64 +           \
                                    (((4 + quad) ^ lx7) * 8)];                 \
    _Pragma("unroll")                                                          \
    for (int nt = 0; nt < 4; ++nt)                                             \
      bf1[nt] = *(const short8*)&Bb[(wn * 64 + nt * 16 + l16) * 64 +           \
                                    (((4 + quad) ^ lx7) * 8)];                 \
    if (st2) { gl_lds16(gA[3] + kk2, &As[nx2][lAo[3]]);                        \
               gl_lds16(gB[0] + kk2, &Bs[nx2][lBo[0]]);                        \
               gl_lds16(gB[1] + kk2, &Bs[nx2][lBo[1]]); }                      \
    __builtin_amdgcn_s_barrier();                                              \
    asm volatile("s_waitcnt lgkmcnt(0)");                                      \
    __builtin_amdgcn_s_setprio(1);                                             \
    _Pragma("unroll")                                                          \
    for (int nt = 0; nt < 4; ++nt)                                             \
      _Pragma("unroll")                                                        \
      for (int mt = 0; mt < 4; ++mt)                                           \
        acc[mt][nt] = __builtin_amdgcn_mfma_f32_16x16x32_bf16(                 \
            af1[mt], bf1[nt], acc[mt][nt], 0, 0, 0);                           \
    __builtin_amdgcn_s_setprio(0);                                             \
    if (st1) {                                                                 \
      if (st2) asm volatile("s_waitcnt vmcnt(6)" ::: "memory");                \
      else     asm volatile("s_waitcnt vmcnt(0)" ::: "memory");                \
    }                                                                          \
    __builtin_amdgcn_s_barrier();                                              \
    cur3 = cur3 + 1 >= 3 ? 0 : cur3 + 1;                                       \
  }

// ---------------- batched QKV GEMM, fp32 A with fused cvt -------------------
// A fp32 pipeline (2-tile lookahead, named reg slots R0/R1, loop unrolled x2):
//   tile t phase0: issue 8 fp32 loads A(t+2) -> R{t&1} (pinned by mem fence);
//   tile t phase1: issue B(t+2) gl_lds16, then cvt R{(t+1)&1} (=A(t+1), loaded
//   at t-1: ~1000cy cover) -> ds_write As[(t+1)&1]. End of tile: counted
//   vmcnt(10) (= A(t+2)x8 + B(t+2)x2 in flight) publishes B(t+1); A-writes
//   published by writer's own lgkmcnt(0) + end barrier. Never drains to 0 in
//   steady state. Same RNE cvt + same MFMA order as before -> bitwise output.
__global__ __launch_bounds__(512, 1) void gemmqkv_k(
    const float* __restrict__ Aq, const float* __restrict__ Ak,
    const float* __restrict__ Av,
    const unsigned short* __restrict__ Bq, const unsigned short* __restrict__ Bk,
    const unsigned short* __restrict__ Bv,
    const float* __restrict__ biq, const float* __restrict__ bik,
    const float* __restrict__ biv,
    unsigned short* __restrict__ Cq, unsigned short* __restrict__ Ck,
    unsigned short* __restrict__ Cv, float qalpha)
{
  constexpr int K = 2048, N = 2048;
  // A 2-ring (64KB) + B 3-ring (48KB) = 112 KiB, one contiguous block so the
  // VT epilogue's [128][264] transpose staging (67.6KB) fits from the base.
  __shared__ __align__(16) unsigned short smem[2 * 256 * 64 + 3 * 128 * 64];
  unsigned short (*As)[256 * 64] = (unsigned short (*)[256 * 64])smem;
  unsigned short (*Bs)[128 * 64] = (unsigned short (*)[128 * 64])(smem + 2 * 256 * 64);

  const int tid  = threadIdx.x;
  const int lane = tid & 63;
  const int wave = tid >> 6;
  const int quad = lane >> 4;
  const int l16  = lane & 15;
  const int lx7  = l16 & 7;
  const int wm   = wave >> 1, wn = wave & 1;

  const float* A; const unsigned short* Bt; const float* bias;
  unsigned short* C; float alpha = 1.0f; bool vt = false;
  if (blockIdx.z == 0)      { A = Aq; Bt = Bq; bias = biq; C = Cq; alpha = qalpha; }
  else if (blockIdx.z == 1) { A = Ak; Bt = Bk; bias = bik; C = Ck; }
  else                      { A = Av; Bt = Bv; bias = biv; C = Cv; vt = true; }

  // XCD-cluster swizzle (bijective on 16x16): XCD = lin%8 gets 8x4 rectangle.
  const int lin  = (int)(blockIdx.y * 16 + blockIdx.x);
  const int xcd  = lin & 7;
  const int slot = lin >> 3;
  const int bx = (xcd & 1) * 8 + (slot & 7);
  const int by = (xcd >> 1) * 4 + (slot >> 3);
  const long bm = (long)by * 256;
  const long bn = (long)bx * 128;

  // B staging plan (gl_lds16, 2 chunks/thread/tile)
  const unsigned short* gB[2]; int lBo[2];
#pragma unroll
  for (int j = 0; j < 2; ++j) {
    const int pb = (wave * 2 + j) * 64 + lane;
    const int r = pb >> 3, cp = pb & 7, cs = cp ^ (r & 7);
    gB[j]  = Bt + (bn + r) * (long)K + cs * 8;
    lBo[j] = pb * 8;
  }

  // A fp32 plan: row = tid>>1 (0..255), 32-col half = tid&1
  const int arow = tid >> 1;
  const int ah   = tid & 1;
  const float* gAf = A + (bm + arow) * (long)K + ah * 32;
  int wOff[4];
#pragma unroll
  for (int c2 = 0; c2 < 4; ++c2) {
    const int c = ah * 4 + c2;
    wOff[c2] = (arow * 8 + (c ^ (arow & 7))) * 8;
  }

  floatx4 acc[4][4];
#pragma unroll
  for (int i = 0; i < 4; ++i)
#pragma unroll
    for (int j = 0; j < 4; ++j) acc[i][j] = (floatx4){0.f, 0.f, 0.f, 0.f};

  constexpr int NT = K >> 6;   // 32 (even)
  float4 R0[8], R1[8];

#define LOADA(Rg, kt) do {                                                    \
    _Pragma("unroll")                                                          \
    for (int j = 0; j < 8; ++j)                                                \
      Rg[j] = *(const float4*)(gAf + (long)(kt) * 64 + j * 4);                 \
    asm volatile("" ::: "memory");  /* pin issue point for vmcnt counting */   \
  } while (0)
#define CVTA(Rg, slotd) do {                                                  \
    _Pragma("unroll")                                                          \
    for (int c2 = 0; c2 < 4; ++c2)                                             \
      *(short8*)&As[slotd][wOff[c2]] = cvt8(Rg[2 * c2], Rg[2 * c2 + 1]);       \
  } while (0)

  // prologue: A(0)->R0, B(0), A(1)->R1, B(1); cvt R0 -> As[0]; publish B(0)
  LOADA(R0, 0);
  gl_lds16(gB[0], &Bs[0][lBo[0]]);
  gl_lds16(gB[1], &Bs[0][lBo[1]]);
  LOADA(R1, 1);
  gl_lds16(gB[0] + 64, &Bs[1][lBo[0]]);
  gl_lds16(gB[1] + 64, &Bs[1][lBo[1]]);
  CVTA(R0, 0);                                     // compiler waits A(0) regs
  asm volatile("s_waitcnt lgkmcnt(0)" ::: "memory");
  asm volatile("s_waitcnt vmcnt(10)" ::: "memory"); // B(0) landed; A(1)+B(1) fly
  __builtin_amdgcn_s_barrier();

#define QKV_TILE(ASLOT, RLOAD, RCVT, WSLOT, TT) do {                           \
    int nx2 = cur3 + 2; if (nx2 >= 3) nx2 -= 3;                                \
    const bool st2 = (TT + 2) < NT;                                            \
    const bool st1 = (TT + 1) < NT;                                            \
    const unsigned short* Ab = As[ASLOT];                                      \
    const unsigned short* Bb = Bs[cur3];                                       \
    /* phase 0 (ks=0): issue A(t+2) fp32 */                                    \
    short8 af0[4], bf0[4];                                                     \
    _Pragma("unroll")                                                          \
    for (int mt = 0; mt < 4; ++mt)                                             \
      af0[mt] = *(const short8*)&Ab[(wm * 64 + mt * 16 + l16) * 64 +           \
                                    ((quad ^ lx7) * 8)];                       \
    _Pragma("unroll")                                                          \
    for (int nt = 0; nt < 4; ++nt)                                             \
      bf0[nt] = *(const short8*)&Bb[(wn * 64 + nt * 16 + l16) * 64 +           \
                                    ((quad ^ lx7) * 8)];                       \
    if (st2) LOADA(RLOAD, TT + 2);                                             \
    __builtin_amdgcn_s_barrier();                                              \
    asm volatile("s_waitcnt lgkmcnt(0)");                                      \
    __builtin_amdgcn_s_setprio(1);                                             \
    _Pragma("unroll")                                                          \
    for (int nt = 0; nt < 4; ++nt)                                             \
      _Pragma("unroll")                                                        \
      for (int mt = 0; mt < 4; ++mt)                                           \
        acc[mt][nt] = __builtin_amdgcn_mfma_f32_16x16x32_bf16(                 \
            af0[mt], bf0[nt], acc[mt][nt], 0, 0, 0);                           \
    __builtin_amdgcn_s_setprio(0);                                             \
    __builtin_amdgcn_s_barrier();                                              \
    /* phase 1 (ks=1): issue B(t+2), cvt A(t+1) -> LDS */                      \
    short8 af1[4], bf1[4];                                                     \
    _Pragma("unroll")                                                          \
    for (int mt = 0; mt < 4; ++mt)                                             \
      af1[mt] = *(const short8*)&Ab[(wm * 64 + mt * 16 + l16) * 64 +           \
                                    (((4 + quad) ^ lx7) * 8)];                 \
    _Pragma("unroll")                                                          \
    for (int nt = 0; nt < 4; ++nt)                                             \
      bf1[nt] = *(const short8*)&Bb[(wn * 64 + nt * 16 + l16) * 64 +           \
                                    (((4 + quad) ^ lx7) * 8)];                 \
    if (st2) { gl_lds16(gB[0] + (long)(TT + 2) * 64, &Bs[nx2][lBo[0]]);        \
               gl_lds16(gB[1] + (long)(TT + 2) * 64, &Bs[nx2][lBo[1]]); }      \
    if (st1) CVTA(RCVT, WSLOT);                                                \
    __builtin_amdgcn_s_barrier();                                              \
    asm volatile("s_waitcnt lgkmcnt(0)");                                      \
    __builtin_amdgcn_s_setprio(1);                                             \
    _Pragma("unroll")                                                          \
    for (int nt = 0; nt < 4; ++nt)                                             \
      _Pragma("unroll")                                                        \
      for (int mt = 0; mt < 4; ++mt)                                           \
        acc[mt][nt] = __builtin_amdgcn_mfma_f32_16x16x32_bf16(                 \
            af1[mt], bf1[nt], acc[mt][nt], 0, 0, 0);                           \
    __builtin_amdgcn_s_setprio(0);                                             \
    if (st1) {                                                                 \
      if (st2) asm volatile("s_waitcnt vmcnt(10)" ::: "memory");               \
      else     asm volatile("s_waitcnt vmcnt(0)" ::: "memory");                \
    }                                                                          \
    __builtin_amdgcn_s_barrier();                                              \
    cur3 = cur3 + 1 >= 3 ? 0 : cur3 + 1;                                       \
  } while (0)

  int cur3 = 0;
#pragma unroll 1
  for (int t = 0; t < NT; t += 2) {
    QKV_TILE(0, R0, R1, 1, t);         // even tile: read As[0], write As[1]
    QKV_TILE(1, R1, R0, 0, t + 1);     // odd tile:  read As[1], write As[0]
  }

  if (vt) {
    __syncthreads();
    unsigned short* Ct = smem;  // [128 col][264] transpose staging
#pragma unroll
    for (int nt = 0; nt < 4; ++nt) {
      const int col_l = wn * 64 + nt * 16 + l16;
      const float bval = bias[bn + col_l];
#pragma unroll
      for (int mt = 0; mt < 4; ++mt) {
        const int row_l = wm * 64 + mt * 16 + quad * 4;
#pragma unroll
        for (int rg = 0; rg < 4; ++rg)
          Ct[col_l * 264 + row_l + rg] = (unsigned short)f2bf((acc[mt][nt][rg] + bval) * alpha);
      }
    }
    __syncthreads();
    const int b  = (int)(bm >> 11);
    const int s0 = (int)(bm & 2047);
    const int d   = tid >> 2;   // 0..127
    const int seg = tid & 3;
    unsigned short* dst = C +
        ((long)(b * 16 + bx) * 128 + d) * 2048 + s0 + seg * 64;
    const unsigned short* src = &Ct[d * 264 + seg * 64];
#pragma unroll
    for (int c = 0; c < 8; ++c)
      *(uint4*)(dst + c * 8) = *(const uint4*)(src + c * 8);
  } else {
#pragma unroll
    for (int nt = 0; nt < 4; ++nt) {
      const long col = bn + wn * 64 + nt * 16 + l16;
      const float bval = bias[col];
#pragma unroll
      for (int mt = 0; mt < 4; ++mt) {
#pragma unroll
        for (int rg = 0; rg < 4; ++rg) {
          const long row = bm + wm * 64 + mt * 16 + quad * 4 + rg;
          C[row * (long)N + col] = (unsigned short)f2bf((acc[mt][nt][rg] + bval) * alpha);
        }
      }
    }
  }
#undef QKV_TILE
#undef LOADA
#undef CVTA
}

// ---------------- single GEMM (out-proj): bf16 A -> fp32 out ----------------
__global__ __launch_bounds__(512, 1) void gemmo_k(
    const unsigned short* __restrict__ A, const unsigned short* __restrict__ Bt,
    const float* __restrict__ bias, float* __restrict__ C)
{
  constexpr int K = 2048, N = 2048;
  __shared__ __align__(16) unsigned short As[3][256 * 64];
  __shared__ __align__(16) unsigned short Bs[3][128 * 64];

  const int tid  = threadIdx.x;
  const int lane = tid & 63;
  const int wave = tid >> 6;
  const int quad = lane >> 4;
  const int l16  = lane & 15;
  const int lx7  = l16 & 7;
  const int wm   = wave >> 1, wn = wave & 1;

  const int lin  = (int)(blockIdx.y * 16 + blockIdx.x);
  const int xcd  = lin & 7;
  const int slot = lin >> 3;
  const int bx = (xcd & 1) * 8 + (slot & 7);
  const int by = (xcd >> 1) * 4 + (slot >> 3);
  const long bm = (long)by * 256;
  const long bn = (long)bx * 128;

  GEMM_CORE(A, Bt)

#pragma unroll
  for (int nt = 0; nt < 4; ++nt) {
    const long col = bn + wn * 64 + nt * 16 + l16;
    const float bval = bias[col];
#pragma unroll
    for (int mt = 0; mt < 4; ++mt) {
#pragma unroll
      for (int rg = 0; rg < 4; ++rg) {
        const long row = bm + wm * 64 + mt * 16 + quad * 4 + rg;
        C[row * (long)N + col] = (acc[mt][nt][rg] + bval);
      }
    }
  }
}

// ---------------- fallback GEMM (fp32 operands) -----------------------------
template<bool A_BF16, bool OUT_BF16, bool VT_OUT>
__global__ __launch_bounds__(256, 2) void gemm_bias_k(
    const void* __restrict__ Aptr, const float* __restrict__ Bt,
    const float* __restrict__ bias, void* __restrict__ Cptr,
    int M, int N, int K, float alpha)
{
  __shared__ __align__(16) unsigned short smem[128 * 136];
  unsigned short* As = smem;
  unsigned short* Bs = smem + 128 * 40;

  const int tid  = threadIdx.x;
  const int lane = tid & 63;
  const int wave = tid >> 6;
  const int quad = lane >> 4;
  const int l16  = lane & 15;
  const int wr   = wave >> 1, wc = wave & 1;
  const long bm  = (long)blockIdx.y * 128;
  const long bn  = (long)blockIdx.x * 128;

  floatx4 acc[4][4];
#pragma unroll
  for (int i = 0; i < 4; ++i)
#pragma unroll
    for (int j = 0; j < 4; ++j) acc[i][j] = (floatx4){0.f, 0.f, 0.f, 0.f};

  const int srow = tid >> 2;
  const int cc   = tid & 3;

  for (int k0 = 0; k0 < K; k0 += 32) {
    __syncthreads();
#pragma unroll
    for (int r = 0; r < 2; ++r) {
      const int row = srow + r * 64;
      short8 av, bv;
      if (A_BF16) {
        av = *(const short8*)((const unsigned short*)Aptr + (bm + row) * (long)K + k0 + cc * 8);
      } else {
        const float* ap = (const float*)Aptr + (bm + row) * (long)K + k0 + cc * 8;
        av = cvt8(*(const float4*)ap, *(const float4*)(ap + 4));
      }
      {
        const float* bp = Bt + (bn + row) * (long)K + k0 + cc * 8;
        bv = cvt8(*(const float4*)bp, *(const float4*)(bp + 4));
      }
      *(short8*)&As[row * 40 + cc * 8] = av;
      *(short8*)&Bs[row * 40 + cc * 8] = bv;
    }
    __syncthreads();

    short8 af[4], bf[4];
#pragma unroll
    for (int t = 0; t < 4; ++t) {
      af[t] = *(const short8*)&As[(wr * 64 + t * 16 + l16) * 40 + quad * 8];
      bf[t] = *(const short8*)&Bs[(wc * 64 + t * 16 + l16) * 40 + quad * 8];
    }
#pragma unroll
    for (int mt = 0; mt < 4; ++mt)
#pragma unroll
      for (int nt = 0; nt < 4; ++nt)
        acc[mt][nt] = __builtin_amdgcn_mfma_f32_16x16x32_bf16(af[mt], bf[nt], acc[mt][nt], 0, 0, 0);
  }

  if (VT_OUT) {
    __syncthreads();
    unsigned short* Ct = smem;
#pragma unroll
    for (int nt = 0; nt < 4; ++nt) {
      const long col = bn + wc * 64 + nt * 16 + l16;
      const float bval = bias[col];
      const int col_l = wc * 64 + nt * 16 + l16;
#pragma unroll
      for (int mt = 0; mt < 4; ++mt) {
        const int row_l = wr * 64 + mt * 16 + quad * 4;
#pragma unroll
        for (int rg = 0; rg < 4; ++rg)
          Ct[col_l * 136 + row_l + rg] = (unsigned short)f2bf((acc[mt][nt][rg] + bval) * alpha);
      }
    }
    __syncthreads();
    const int b  = (int)(bm >> 11);
    const int s0 = (int)(bm & 2047);
    const int r    = tid >> 1;
    const int half = tid & 1;
    unsigned short* dst = (unsigned short*)Cptr +
        ((long)(b * 16 + blockIdx.x) * 128 + r) * 2048 + s0 + half * 64;
    const unsigned short* src = &Ct[r * 136 + half * 64];
#pragma unroll
    for (int c = 0; c < 8; ++c)
      *(uint4*)(dst + c * 8) = *(const uint4*)(src + c * 8);
  } else {
#pragma unroll
    for (int nt = 0; nt < 4; ++nt) {
      const long col = bn + wc * 64 + nt * 16 + l16;
      const float bval = bias[col];
#pragma unroll
      for (int mt = 0; mt < 4; ++mt) {
#pragma unroll
        for (int rg = 0; rg < 4; ++rg) {
          const long row = bm + wr * 64 + mt * 16 + quad * 4 + rg;
          const float v = (acc[mt][nt][rg] + bval) * alpha;
          if (OUT_BF16) ((unsigned short*)Cptr)[row * (long)N + col] = (unsigned short)f2bf(v);
          else          ((float*)Cptr)[row * (long)N + col] = v;
        }
      }
    }
  }
}

// ---------------- flash attention: shuffle-free common path -----------------
__global__ __launch_bounds__(256, 2) void flash_attn_k(
    const unsigned short* __restrict__ Q,
    const unsigned short* __restrict__ Kp,
    const unsigned short* __restrict__ Vt,
    unsigned short* __restrict__ O)
{
  constexpr int S = 2048, D = 2048, HD = 128;
  constexpr int PS = 72;  // Ps stride (shorts)

  __shared__ __align__(16) unsigned short Ks[2][64 * 128];   // [k][d], swizzled
  __shared__ __align__(16) unsigned short Vst[2][128 * 64];  // [d][k], swizzled
  __shared__ __align__(16) unsigned short Ps[64 * PS];       // [q_local][k]

  const int tid  = threadIdx.x;
  const int lane = tid & 63;
  const int w    = tid >> 6;
  const int quad = lane >> 4;
  const int l16  = lane & 15;
  const int lx7  = l16 & 7;

  // XCD-aware remap: bijective (bx,by) -> (bh, qsel) with bh fixed per bx&7
  const int bx  = blockIdx.x;            // 0..15
  const int by  = blockIdx.y;            // 0..31
  const int idx = by * 2 + (bx >> 3);    // 0..63
  const int bh  = (bx & 7) * 4 + (idx >> 4);
  const int qsel = idx & 15;

  const long headoff = (long)(bh >> 4) * S * D + (long)(bh & 15) * HD;
  const long vtoff   = (long)bh * HD * S;

  const unsigned short* gK[4]; int oK[4];
  const unsigned short* gV[4]; int oV[4];
#pragma unroll
  for (int i = 0; i < 4; ++i) {
    const int p = (w * 4 + i) * 64 + lane;          // 0..1023
    { const int r = p >> 4, cp = p & 15, c = cp ^ (r & 7);
      gK[i] = Kp + headoff + (long)r * D + c * 8;  oK[i] = p * 8; }
    { const int r = p >> 3, cp = p & 7, c = cp ^ (r & 7);
      gV[i] = Vt + vtoff + (long)r * S + c * 8;    oV[i] = p * 8; }
  }

#pragma unroll 1
  for (int half = 0; half < 2; ++half) {
    const int qt = half ? (31 - qsel) : qsel;
    const int qbase = qt * 64;
    const int qrow  = qbase + w * 16 + l16;   // this lane's q row
    const int qloc  = w * 16 + l16;

    short8 aq[4];
    {
      const unsigned short* qp = Q + headoff + (long)qrow * D;
#pragma unroll
      for (int ks = 0; ks < 4; ++ks)
        aq[ks] = *(const short8*)(qp + ks * 32 + quad * 8);
    }

    floatx4 o_acc[8];
#pragma unroll
    for (int t = 0; t < 8; ++t) o_acc[t] = (floatx4){0.f, 0.f, 0.f, 0.f};
    float m_i = -INFINITY;   // row-uniform (updates use row-reduced max)
    float l_p = 0.f;         // per-lane partial of l_i

#pragma unroll
    for (int i = 0; i < 4; ++i) gl_lds16(gK[i], &Ks[0][oK[i]]);
#pragma unroll
    for (int i = 0; i < 4; ++i) gl_lds16(gV[i], &Vst[0][oV[i]]);

    for (int kt = 0; kt <= qt; ++kt) {
      const int cur = kt & 1;
      const int kbase = kt * 64;
      if (kt < qt) {
        const long kb = (long)(kt + 1) * 64;
        const int nb = cur ^ 1;
#pragma unroll
        for (int i = 0; i < 4; ++i) gl_lds16(gK[i] + kb * D, &Ks[nb][oK[i]]);
#pragma unroll
        for (int i = 0; i < 4; ++i) gl_lds16(gV[i] + kb, &Vst[nb][oV[i]]);
        asm volatile("s_waitcnt vmcnt(8)" ::: "memory");
      } else {
        asm volatile("s_waitcnt vmcnt(0)" ::: "memory");
      }
      __builtin_amdgcn_s_barrier();   // B1: tile kt visible to all waves

      const unsigned short* Kb = &Ks[cur][0];
      const unsigned short* Vb = &Vst[cur][0];

      floatx4 sc[4];
#pragma unroll
      for (int nt = 0; nt < 4; ++nt) sc[nt] = (floatx4){0.f, 0.f, 0.f, 0.f};
      __builtin_amdgcn_s_setprio(1);
#pragma unroll
      for (int nt = 0; nt < 4; ++nt) {
        const int krow = nt * 16 + l16;
#pragma unroll
        for (int ks = 0; ks < 4; ++ks) {
          const int cp = (ks * 4 + quad) ^ lx7;
          short8 kf = *(const short8*)&Kb[krow * 128 + cp * 8];
          sc[nt] = __builtin_amdgcn_mfma_f32_16x16x32_bf16(kf, aq[ks], sc[nt], 0, 0, 0);
        }
      }
      __builtin_amdgcn_s_setprio(0);

      float sv[4][4];
      float lmax = -INFINITY;
      if (kt == qt) {
        const int kg0 = kbase + quad * 4;
#pragma unroll
        for (int nt = 0; nt < 4; ++nt)
#pragma unroll
          for (int rg = 0; rg < 4; ++rg) {
            float v = sc[nt][rg];
            if (kg0 + nt * 16 + rg > qrow) v = -INFINITY;
            sv[nt][rg] = v;
            lmax = fmaxf(lmax, v);
          }
      } else {
#pragma unroll
        for (int nt = 0; nt < 4; ++nt)
#pragma unroll
          for (int rg = 0; rg < 4; ++rg) {
            sv[nt][rg] = sc[nt][rg];
            lmax = fmaxf(lmax, sc[nt][rg]);
          }
      }

      float al = 1.0f;
      if (__any(lmax > m_i + 8.0f)) {
        float rmax = fmaxf(lmax, __shfl_xor(lmax, 16));
        rmax = fmaxf(rmax, __shfl_xor(rmax, 32));
        const float mn = fmaxf(m_i, rmax);
        al = exp2f(m_i - mn);
        m_i = mn;
#pragma unroll
        for (int t = 0; t < 8; ++t)
#pragma unroll
          for (int rg = 0; rg < 4; ++rg) o_acc[t][rg] *= al;
      }

      float rsum = 0.f;
#pragma unroll
      for (int nt = 0; nt < 4; ++nt) {
        float p0 = exp2f(sv[nt][0] - m_i), p1 = exp2f(sv[nt][1] - m_i);
        float p2 = exp2f(sv[nt][2] - m_i), p3 = exp2f(sv[nt][3] - m_i);
        rsum += (p0 + p1) + (p2 + p3);
        *(short4b*)&Ps[qloc * PS + nt * 16 + quad * 4] = pack4bf(p0, p1, p2, p3);
      }
      l_p = l_p * al + rsum;

      short8 pf[2];
#pragma unroll
      for (int ks = 0; ks < 2; ++ks)
        pf[ks] = *(const short8*)&Ps[qloc * PS + ks * 32 + quad * 8];

      __builtin_amdgcn_s_setprio(1);
#pragma unroll
      for (int t = 0; t < 8; ++t) {
        const int drow = t * 16 + l16;
#pragma unroll
        for (int ks = 0; ks < 2; ++ks) {
          const int cp = (ks * 4 + quad) ^ lx7;
          short8 vf = *(const short8*)&Vb[drow * 64 + cp * 8];
          o_acc[t] = __builtin_amdgcn_mfma_f32_16x16x32_bf16(vf, pf[ks], o_acc[t], 0, 0, 0);
        }
      }
      __builtin_amdgcn_s_setprio(0);
      __builtin_amdgcn_s_barrier();   // B2: all waves done reading buf cur
    }

    float l_i = l_p + __shfl_xor(l_p, 16);
    l_i += __shfl_xor(l_i, 32);
    const float rl = 1.0f / l_i;
    unsigned short* op = O + headoff + (long)qrow * D;
#pragma unroll
    for (int t = 0; t < 8; ++t) {
      *(short4b*)(op + t * 16 + quad * 4) =
          pack4bf(o_acc[t][0] * rl, o_acc[t][1] * rl, o_acc[t][2] * rl, o_acc[t][3] * rl);
    }
  }
}

extern "C" void kernel_launch(void* const* d_in, const int* in_sizes, int n_in,
                              void* d_out, int out_size, void* d_ws, size_t ws_size,
                              hipStream_t stream) {
  const float* query = (const float*)d_in[0];
  const float* key_  = (const float*)d_in[1];
  const float* value = (const float*)d_in[2];
  const float* Wq = (const float*)d_in[3];
  const float* bq = (const float*)d_in[4];
  const float* Wk = (const float*)d_in[5];
  const float* bk = (const float*)d_in[6];
  const float* Wv = (const float*)d_in[7];
  const float* bv = (const float*)d_in[8];
  const float* Wo = (const float*)d_in[9];
  const float* bo = (const float*)d_in[10];
  float* out = (float*)d_out;

  constexpr int Bz = 2, S = 2048, D = 2048;
  constexpr int M = Bz * S;
  constexpr long NELEM = (long)M * D;
  constexpr long WELEM = (long)D * D;

  const float qscale = 0.08838834764831845f * LOG2E;
  dim3 gridG(D / 128, M / 128);

  const size_t need_full = (size_t)(4 * NELEM + 4 * WELEM) * 2;

  if (ws_size >= need_full) {
    unsigned short* Qp  = (unsigned short*)d_ws;
    unsigned short* Kp  = Qp + NELEM;
    unsigned short* Vt  = Kp + NELEM;
    unsigned short* Oa  = Vt + NELEM;
    unsigned short* Wqb = Oa + NELEM;
    unsigned short* Wkb = Wqb + WELEM;
    unsigned short* Wvb = Wkb + WELEM;
    unsigned short* Wob = Wvb + WELEM;

    cvt_k<<<dim3(WELEM / (8 * 256), 4), 256, 0, stream>>>(
        Wq, Wk, Wv, Wo, Wqb, Wkb, Wvb, Wob, (int)WELEM);

    gemmqkv_k<<<dim3(16, 16, 3), 512, 0, stream>>>(
        query, key_, value, Wqb, Wkb, Wvb, bq, bk, bv, Qp, Kp, Vt, qscale);

    flash_attn_k<<<dim3(16, 32), 256, 0, stream>>>(Qp, Kp, Vt, Oa);

    gemmo_k<<<dim3(16, 16), 512, 0, stream>>>(Oa, Wob, bo, out);
  } else {
    unsigned short* Qp = (unsigned short*)d_ws;
    unsigned short* Kp = Qp + NELEM;
    unsigned short* Vt = Kp + NELEM;
    unsigned short* Oa = Vt + NELEM;

    gemm_bias_k<false, true, false><<<gridG, 256, 0, stream>>>(query, Wq, bq, Qp, M, D, D, qscale);
    gemm_bias_k<false, true, false><<<gridG, 256, 0, stream>>>(key_,  Wk, bk, Kp, M, D, D, 1.0f);
    gemm_bias_k<false, true, true ><<<gridG, 256, 0, stream>>>(value, Wv, bv, Vt, M, D, D, 1.0f);

    flash_attn_k<<<dim3(16, 32), 256, 0, stream>>>(Qp, Kp, Vt, Oa);

    gemm_bias_k<true, false, false><<<gridG, 256, 0, stream>>>(Oa, Wo, bo, out, M, D, D, 1.0f);
  }
}

// Round 7
// 403.281 us; speedup vs baseline: 1.4380x; 1.4380x over previous
//
#include <hip/hip_runtime.h>
#include <hip/hip_bf16.h>

// B=2, S=2048, D=2048, H=16, HD=128, causal MHA with 4 linear projections.
// one cvt launch (uniform grid, 3 activations + 4 weights) -> batched QKV GEMM
// (ks-split 2-phase, ALL 16 frag reads hoisted to tile start so ks1 latency
// hides under ks0 MFMA; counted vmcnt; XCD-clustered blocks; V transposed per
// head) -> flash attn (transposed scores, per-lane softmax rows, lane-partial
// l_i, dbuf K/V, XCD-grouped heads) -> out-proj GEMM (same schedule).

#define LOG2E 1.44269504088896340736f

typedef __attribute__((ext_vector_type(8))) short short8;    // 8 x bf16
typedef __attribute__((ext_vector_type(4))) short short4b;   // 4 x bf16
typedef __attribute__((ext_vector_type(4))) float floatx4;   // MFMA acc

__device__ __forceinline__ short f2bf(float f) {
  unsigned int u = __builtin_bit_cast(unsigned int, f);
  u += 0x7FFFu + ((u >> 16) & 1u);  // RNE
  return (short)(u >> 16);
}

__device__ __forceinline__ short8 cvt8(float4 f0, float4 f1) {
  return (short8){f2bf(f0.x), f2bf(f0.y), f2bf(f0.z), f2bf(f0.w),
                  f2bf(f1.x), f2bf(f1.y), f2bf(f1.z), f2bf(f1.w)};
}

__device__ __forceinline__ short4b pack4bf(float a, float b, float c, float d) {
  __hip_bfloat162 lo = __float22bfloat162_rn(float2{a, b});
  __hip_bfloat162 hi = __float22bfloat162_rn(float2{c, d});
  short4b r;
  r[0] = __builtin_bit_cast(short, lo.x); r[1] = __builtin_bit_cast(short, lo.y);
  r[2] = __builtin_bit_cast(short, hi.x); r[3] = __builtin_bit_cast(short, hi.y);
  return r;
}

__device__ __forceinline__ void gl_lds16(const void* g, void* l) {
  __builtin_amdgcn_global_load_lds(
      (const __attribute__((address_space(1))) unsigned int*)g,
      (__attribute__((address_space(3))) unsigned int*)l, 16, 0, 0);
}

// ---------------- fp32 -> bf16 conversion, 7 tensors, uniform grid ----------
// grid (4096, 7) x 256 thr x 8 elem. Activation slices (y<3, n=nAct) use all
// 4096 blocks; weight slices (n=nW) early-exit past 2048. Fully coalesced,
// one chunk per block (no serial dependent chain).
__global__ __launch_bounds__(256) void cvt7_k(
    const float* __restrict__ s0, const float* __restrict__ s1,
    const float* __restrict__ s2, const float* __restrict__ s3,
    const float* __restrict__ s4, const float* __restrict__ s5,
    const float* __restrict__ s6,
    unsigned short* __restrict__ d0, unsigned short* __restrict__ d1,
    unsigned short* __restrict__ d2, unsigned short* __restrict__ d3,
    unsigned short* __restrict__ d4, unsigned short* __restrict__ d5,
    unsigned short* __restrict__ d6, int nAct, int nW)
{
  const float* s; unsigned short* d; int n;
  switch (blockIdx.y) {
    case 0: s = s0; d = d0; n = nAct; break;
    case 1: s = s1; d = d1; n = nAct; break;
    case 2: s = s2; d = d2; n = nAct; break;
    case 3: s = s3; d = d3; n = nW; break;
    case 4: s = s4; d = d4; n = nW; break;
    case 5: s = s5; d = d5; n = nW; break;
    default: s = s6; d = d6; n = nW; break;
  }
  const long i = ((long)blockIdx.x * 256 + threadIdx.x) * 8;
  if (i >= n) return;
  float4 a = *(const float4*)(s + i);
  float4 b = *(const float4*)(s + i + 4);
  *(short8*)(d + i) = cvt8(a, b);
}

// ============ shared GEMM body (ks-split 2-phase, hoisted reads) =============
// BM=256, BN=128, BK=64, 512 thr = 8 waves (4M x 2N). LDS 3-ring (A+B).
// Per K-tile: ALL 16 frag ds_read_b128 issued at tile start (pinned before the
// phase-0 barrier) -> compiler emits counted lgkmcnt(8) before ks0 MFMA and
// lgkmcnt(0) (already satisfied) before ks1 MFMA: ks1 read latency hides under
// ks0's 16 MFMA. 3 gl_lds16 staged per phase; end-of-tile vmcnt(6) publishes
// t+1 (t+2 in flight; never drains to 0 in steady state). MFMA order per
// accumulator unchanged (ks0 then ks1) -> bitwise-identical output.
#define GEMM_CORE(A_, Bt_)                                                     \
  const unsigned short* gA[4]; int lAo[4];                                     \
  const unsigned short* gB[2]; int lBo[2];                                     \
  _Pragma("unroll")                                                            \
  for (int j = 0; j < 4; ++j) {                                                \
    const int pa = ((j >> 1) * 16 + wave * 2 + (j & 1)) * 64 + lane;           \
    const int r = pa >> 3, cp = pa & 7, cs = cp ^ (r & 7);                     \
    gA[j]  = A_ + (bm + r) * (long)K + cs * 8;                                 \
    lAo[j] = pa * 8;                                                           \
  }                                                                            \
  _Pragma("unroll")                                                            \
  for (int j = 0; j < 2; ++j) {                                                \
    const int pb = (wave * 2 + j) * 64 + lane;                                 \
    const int r = pb >> 3, cp = pb & 7, cs = cp ^ (r & 7);                     \
    gB[j]  = Bt_ + (bn + r) * (long)K + cs * 8;                                \
    lBo[j] = pb * 8;                                                           \
  }                                                                            \
  floatx4 acc[4][4];                                                           \
  _Pragma("unroll")                                                            \
  for (int i = 0; i < 4; ++i)                                                  \
    _Pragma("unroll")                                                          \
    for (int j = 0; j < 4; ++j) acc[i][j] = (floatx4){0.f, 0.f, 0.f, 0.f};     \
  const int NT = K >> 6;                                                       \
  _Pragma("unroll")                                                            \
  for (int j = 0; j < 4; ++j) gl_lds16(gA[j], &As[0][lAo[j]]);                 \
  _Pragma("unroll")                                                            \
  for (int j = 0; j < 2; ++j) gl_lds16(gB[j], &Bs[0][lBo[j]]);                 \
  if (NT > 1) {                                                                \
    _Pragma("unroll")                                                          \
    for (int j = 0; j < 4; ++j) gl_lds16(gA[j] + 64, &As[1][lAo[j]]);          \
    _Pragma("unroll")                                                          \
    for (int j = 0; j < 2; ++j) gl_lds16(gB[j] + 64, &Bs[1][lBo[j]]);          \
    asm volatile("s_waitcnt vmcnt(6)" ::: "memory");                           \
  } else {                                                                     \
    asm volatile("s_waitcnt vmcnt(0)" ::: "memory");                           \
  }                                                                            \
  __builtin_amdgcn_s_barrier();                                                \
  int cur3 = 0;                                                                \
  for (int t = 0; t < NT; ++t) {                                               \
    int nx2 = cur3 + 2; if (nx2 >= 3) nx2 -= 3;                                \
    const long kk2 = (long)(t + 2) * 64;                                       \
    const bool st2 = (t + 2) < NT;                                             \
    const bool st1 = (t + 1) < NT;                                             \
    const unsigned short* Ab = As[cur3];                                       \
    const unsigned short* Bb = Bs[cur3];                                       \
    /* ---- all 16 fragment reads at tile start ---- */                        \
    short8 af0[4], bf0[4], af1[4], bf1[4];                                     \
    _Pragma("unroll")                                                          \
    for (int mt = 0; mt < 4; ++mt)                                             \
      af0[mt] = *(const short8*)&Ab[(wm * 64 + mt * 16 + l16) * 64 +           \
                                    ((quad ^ lx7) * 8)];                       \
    _Pragma("unroll")                                                          \
    for (int nt = 0; nt < 4; ++nt)                                             \
      bf0[nt] = *(const short8*)&Bb[(wn * 64 + nt * 16 + l16) * 64 +           \
                                    ((quad ^ lx7) * 8)];                       \
    _Pragma("unroll")                                                          \
    for (int mt = 0; mt < 4; ++mt)                                             \
      af1[mt] = *(const short8*)&Ab[(wm * 64 + mt * 16 + l16) * 64 +           \
                                    (((4 + quad) ^ lx7) * 8)];                 \
    _Pragma("unroll")                                                          \
    for (int nt = 0; nt < 4; ++nt)                                             \
      bf1[nt] = *(const short8*)&Bb[(wn * 64 + nt * 16 + l16) * 64 +           \
                                    (((4 + quad) ^ lx7) * 8)];                 \
    if (st2) { gl_lds16(gA[0] + kk2, &As[nx2][lAo[0]]);                        \
               gl_lds16(gA[1] + kk2, &As[nx2][lAo[1]]);                        \
               gl_lds16(gA[2] + kk2, &As[nx2][lAo[2]]); }                      \
    __builtin_amdgcn_s_barrier();                                              \
    /* ---- phase 0 (ks=0): compiler waits lgkmcnt(8) ---- */                  \
    __builtin_amdgcn_s_setprio(1);                                             \
    _Pragma("unroll")                                                          \
    for (int nt = 0; nt < 4; ++nt)                                             \
      _Pragma("unroll")                                                        \
      for (int mt = 0; mt < 4; ++mt)                                           \
        acc[mt][nt] = __builtin_amdgcn_mfma_f32_16x16x32_bf16(                 \
            af0[mt], bf0[nt], acc[mt][nt], 0, 0, 0);                           \
    __builtin_amdgcn_s_setprio(0);                                             \
    __builtin_amdgcn_s_barrier();                                              \
    /* ---- phase 1 (ks=1): frags already resident ---- */                     \
    if (st2) { gl_lds16(gA[3] + kk2, &As[nx2][lAo[3]]);                        \
               gl_lds16(gB[0] + kk2, &Bs[nx2][lBo[0]]);                        \
               gl_lds16(gB[1] + kk2, &Bs[nx2][lBo[1]]); }                      \
    __builtin_amdgcn_s_setprio(1);                                             \
    _Pragma("unroll")                                                          \
    for (int nt = 0; nt < 4; ++nt)                                             \
      _Pragma("unroll")                                                        \
      for (int mt = 0; mt < 4; ++mt)                                           \
        acc[mt][nt] = __builtin_amdgcn_mfma_f32_16x16x32_bf16(                 \
            af1[mt], bf1[nt], acc[mt][nt], 0, 0, 0);                           \
    __builtin_amdgcn_s_setprio(0);                                             \
    if (st1) {                                                                 \
      if (st2) asm volatile("s_waitcnt vmcnt(6)" ::: "memory");                \
      else     asm volatile("s_waitcnt vmcnt(0)" ::: "memory");                \
    }                                                                          \
    __builtin_amdgcn_s_barrier();                                              \
    cur3 = cur3 + 1 >= 3 ? 0 : cur3 + 1;                                       \
  }

// ---------------- batched QKV GEMM (z = 0:Q, 1:K, 2:V-transposed) -----------
__global__ __launch_bounds__(512, 1) void gemmqkv_k(
    const unsigned short* __restrict__ Aq, const unsigned short* __restrict__ Ak,
    const unsigned short* __restrict__ Av,
    const unsigned short* __restrict__ Bq, const unsigned short* __restrict__ Bk,
    const unsigned short* __restrict__ Bv,
    const float* __restrict__ biq, const float* __restrict__ bik,
    const float* __restrict__ biv,
    unsigned short* __restrict__ Cq, unsigned short* __restrict__ Ck,
    unsigned short* __restrict__ Cv, float qalpha)
{
  constexpr int K = 2048, N = 2048;
  __shared__ __align__(16) unsigned short As[3][256 * 64];
  __shared__ __align__(16) unsigned short Bs[3][128 * 64];

  const int tid  = threadIdx.x;
  const int lane = tid & 63;
  const int wave = tid >> 6;
  const int quad = lane >> 4;
  const int l16  = lane & 15;
  const int lx7  = l16 & 7;
  const int wm   = wave >> 1, wn = wave & 1;

  const unsigned short* A; const unsigned short* Bt; const float* bias;
  unsigned short* C; float alpha = 1.0f; bool vt = false;
  if (blockIdx.z == 0)      { A = Aq; Bt = Bq; bias = biq; C = Cq; alpha = qalpha; }
  else if (blockIdx.z == 1) { A = Ak; Bt = Bk; bias = bik; C = Ck; }
  else                      { A = Av; Bt = Bv; bias = biv; C = Cv; vt = true; }

  // XCD-cluster swizzle (bijective on 16x16): XCD = lin%8 gets 8x4 rectangle.
  const int lin  = (int)(blockIdx.y * 16 + blockIdx.x);
  const int xcd  = lin & 7;
  const int slot = lin >> 3;
  const int bx = (xcd & 1) * 8 + (slot & 7);
  const int by = (xcd >> 1) * 4 + (slot >> 3);
  const long bm = (long)by * 256;
  const long bn = (long)bx * 128;

  GEMM_CORE(A, Bt)

  if (vt) {
    __syncthreads();
    unsigned short* Ct = &As[0][0];  // [128 col][264] transpose staging
#pragma unroll
    for (int nt = 0; nt < 4; ++nt) {
      const int col_l = wn * 64 + nt * 16 + l16;
      const float bval = bias[bn + col_l];
#pragma unroll
      for (int mt = 0; mt < 4; ++mt) {
        const int row_l = wm * 64 + mt * 16 + quad * 4;
#pragma unroll
        for (int rg = 0; rg < 4; ++rg)
          Ct[col_l * 264 + row_l + rg] = (unsigned short)f2bf((acc[mt][nt][rg] + bval) * alpha);
      }
    }
    __syncthreads();
    const int b  = (int)(bm >> 11);
    const int s0 = (int)(bm & 2047);
    const int d   = tid >> 2;   // 0..127
    const int seg = tid & 3;
    unsigned short* dst = C +
        ((long)(b * 16 + bx) * 128 + d) * 2048 + s0 + seg * 64;
    const unsigned short* src = &Ct[d * 264 + seg * 64];
#pragma unroll
    for (int c = 0; c < 8; ++c)
      *(uint4*)(dst + c * 8) = *(const uint4*)(src + c * 8);
  } else {
#pragma unroll
    for (int nt = 0; nt < 4; ++nt) {
      const long col = bn + wn * 64 + nt * 16 + l16;
      const float bval = bias[col];
#pragma unroll
      for (int mt = 0; mt < 4; ++mt) {
#pragma unroll
        for (int rg = 0; rg < 4; ++rg) {
          const long row = bm + wm * 64 + mt * 16 + quad * 4 + rg;
          C[row * (long)N + col] = (unsigned short)f2bf((acc[mt][nt][rg] + bval) * alpha);
        }
      }
    }
  }
}

// ---------------- single GEMM (out-proj): bf16 A -> fp32 out ----------------
__global__ __launch_bounds__(512, 1) void gemmo_k(
    const unsigned short* __restrict__ A, const unsigned short* __restrict__ Bt,
    const float* __restrict__ bias, float* __restrict__ C)
{
  constexpr int K = 2048, N = 2048;
  __shared__ __align__(16) unsigned short As[3][256 * 64];
  __shared__ __align__(16) unsigned short Bs[3][128 * 64];

  const int tid  = threadIdx.x;
  const int lane = tid & 63;
  const int wave = tid >> 6;
  const int quad = lane >> 4;
  const int l16  = lane & 15;
  const int lx7  = l16 & 7;
  const int wm   = wave >> 1, wn = wave & 1;

  const int lin  = (int)(blockIdx.y * 16 + blockIdx.x);
  const int xcd  = lin & 7;
  const int slot = lin >> 3;
  const int bx = (xcd & 1) * 8 + (slot & 7);
  const int by = (xcd >> 1) * 4 + (slot >> 3);
  const long bm = (long)by * 256;
  const long bn = (long)bx * 128;

  GEMM_CORE(A, Bt)

#pragma unroll
  for (int nt = 0; nt < 4; ++nt) {
    const long col = bn + wn * 64 + nt * 16 + l16;
    const float bval = bias[col];
#pragma unroll
    for (int mt = 0; mt < 4; ++mt) {
#pragma unroll
      for (int rg = 0; rg < 4; ++rg) {
        const long row = bm + wm * 64 + mt * 16 + quad * 4 + rg;
        C[row * (long)N + col] = (acc[mt][nt][rg] + bval);
      }
    }
  }
}

// ---------------- fallback GEMM (fp32 operands) -----------------------------
template<bool A_BF16, bool OUT_BF16, bool VT_OUT>
__global__ __launch_bounds__(256, 2) void gemm_bias_k(
    const void* __restrict__ Aptr, const float* __restrict__ Bt,
    const float* __restrict__ bias, void* __restrict__ Cptr,
    int M, int N, int K, float alpha)
{
  __shared__ __align__(16) unsigned short smem[128 * 136];
  unsigned short* As = smem;
  unsigned short* Bs = smem + 128 * 40;

  const int tid  = threadIdx.x;
  const int lane = tid & 63;
  const int wave = tid >> 6;
  const int quad = lane >> 4;
  const int l16  = lane & 15;
  const int wr   = wave >> 1, wc = wave & 1;
  const long bm  = (long)blockIdx.y * 128;
  const long bn  = (long)blockIdx.x * 128;

  floatx4 acc[4][4];
#pragma unroll
  for (int i = 0; i < 4; ++i)
#pragma unroll
    for (int j = 0; j < 4; ++j) acc[i][j] = (floatx4){0.f, 0.f, 0.f, 0.f};

  const int srow = tid >> 2;
  const int cc   = tid & 3;

  for (int k0 = 0; k0 < K; k0 += 32) {
    __syncthreads();
#pragma unroll
    for (int r = 0; r < 2; ++r) {
      const int row = srow + r * 64;
      short8 av, bv;
      if (A_BF16) {
        av = *(const short8*)((const unsigned short*)Aptr + (bm + row) * (long)K + k0 + cc * 8);
      } else {
        const float* ap = (const float*)Aptr + (bm + row) * (long)K + k0 + cc * 8;
        av = cvt8(*(const float4*)ap, *(const float4*)(ap + 4));
      }
      {
        const float* bp = Bt + (bn + row) * (long)K + k0 + cc * 8;
        bv = cvt8(*(const float4*)bp, *(const float4*)(bp + 4));
      }
      *(short8*)&As[row * 40 + cc * 8] = av;
      *(short8*)&Bs[row * 40 + cc * 8] = bv;
    }
    __syncthreads();

    short8 af[4], bf[4];
#pragma unroll
    for (int t = 0; t < 4; ++t) {
      af[t] = *(const short8*)&As[(wr * 64 + t * 16 + l16) * 40 + quad * 8];
      bf[t] = *(const short8*)&Bs[(wc * 64 + t * 16 + l16) * 40 + quad * 8];
    }
#pragma unroll
    for (int mt = 0; mt < 4; ++mt)
#pragma unroll
      for (int nt = 0; nt < 4; ++nt)
        acc[mt][nt] = __builtin_amdgcn_mfma_f32_16x16x32_bf16(af[mt], bf[nt], acc[mt][nt], 0, 0, 0);
  }

  if (VT_OUT) {
    __syncthreads();
    unsigned short* Ct = smem;
#pragma unroll
    for (int nt = 0; nt < 4; ++nt) {
      const long col = bn + wc * 64 + nt * 16 + l16;
      const float bval = bias[col];
      const int col_l = wc * 64 + nt * 16 + l16;
#pragma unroll
      for (int mt = 0; mt < 4; ++mt) {
        const int row_l = wr * 64 + mt * 16 + quad * 4;
#pragma unroll
        for (int rg = 0; rg < 4; ++rg)
          Ct[col_l * 136 + row_l + rg] = (unsigned short)f2bf((acc[mt][nt][rg] + bval) * alpha);
      }
    }
    __syncthreads();
    const int b  = (int)(bm >> 11);
    const int s0 = (int)(bm & 2047);
    const int r    = tid >> 1;
    const int half = tid & 1;
    unsigned short* dst = (unsigned short*)Cptr +
        ((long)(b * 16 + blockIdx.x) * 128 + r) * 2048 + s0 + half * 64;
    const unsigned short* src = &Ct[r * 136 + half * 64];
#pragma unroll
    for (int c = 0; c < 8; ++c)
      *(uint4*)(dst + c * 8) = *(const uint4*)(src + c * 8);
  } else {
#pragma unroll
    for (int nt = 0; nt < 4; ++nt) {
      const long col = bn + wc * 64 + nt * 16 + l16;
      const float bval = bias[col];
#pragma unroll
      for (int mt = 0; mt < 4; ++mt) {
#pragma unroll
        for (int rg = 0; rg < 4; ++rg) {
          const long row = bm + wr * 64 + mt * 16 + quad * 4 + rg;
          const float v = (acc[mt][nt][rg] + bval) * alpha;
          if (OUT_BF16) ((unsigned short*)Cptr)[row * (long)N + col] = (unsigned short)f2bf(v);
          else          ((float*)Cptr)[row * (long)N + col] = v;
        }
      }
    }
  }
}

// ---------------- flash attention: shuffle-free common path -----------------
__global__ __launch_bounds__(256, 2) void flash_attn_k(
    const unsigned short* __restrict__ Q,
    const unsigned short* __restrict__ Kp,
    const unsigned short* __restrict__ Vt,
    unsigned short* __restrict__ O)
{
  constexpr int S = 2048, D = 2048, HD = 128;
  constexpr int PS = 72;  // Ps stride (shorts)

  __shared__ __align__(16) unsigned short Ks[2][64 * 128];   // [k][d], swizzled
  __shared__ __align__(16) unsigned short Vst[2][128 * 64];  // [d][k], swizzled
  __shared__ __align__(16) unsigned short Ps[64 * PS];       // [q_local][k]

  const int tid  = threadIdx.x;
  const int lane = tid & 63;
  const int w    = tid >> 6;
  const int quad = lane >> 4;
  const int l16  = lane & 15;
  const int lx7  = l16 & 7;

  // XCD-aware remap: bijective (bx,by) -> (bh, qsel) with bh fixed per bx&7
  const int bx  = blockIdx.x;            // 0..15
  const int by  = blockIdx.y;            // 0..31
  const int idx = by * 2 + (bx >> 3);    // 0..63
  const int bh  = (bx & 7) * 4 + (idx >> 4);
  const int qsel = idx & 15;

  const long headoff = (long)(bh >> 4) * S * D + (long)(bh & 15) * HD;
  const long vtoff   = (long)bh * HD * S;

  const unsigned short* gK[4]; int oK[4];
  const unsigned short* gV[4]; int oV[4];
#pragma unroll
  for (int i = 0; i < 4; ++i) {
    const int p = (w * 4 + i) * 64 + lane;          // 0..1023
    { const int r = p >> 4, cp = p & 15, c = cp ^ (r & 7);
      gK[i] = Kp + headoff + (long)r * D + c * 8;  oK[i] = p * 8; }
    { const int r = p >> 3, cp = p & 7, c = cp ^ (r & 7);
      gV[i] = Vt + vtoff + (long)r * S + c * 8;    oV[i] = p * 8; }
  }

#pragma unroll 1
  for (int half = 0; half < 2; ++half) {
    const int qt = half ? (31 - qsel) : qsel;
    const int qbase = qt * 64;
    const int qrow  = qbase + w * 16 + l16;   // this lane's q row
    const int qloc  = w * 16 + l16;

    short8 aq[4];
    {
      const unsigned short* qp = Q + headoff + (long)qrow * D;
#pragma unroll
      for (int ks = 0; ks < 4; ++ks)
        aq[ks] = *(const short8*)(qp + ks * 32 + quad * 8);
    }

    floatx4 o_acc[8];
#pragma unroll
    for (int t = 0; t < 8; ++t) o_acc[t] = (floatx4){0.f, 0.f, 0.f, 0.f};
    float m_i = -INFINITY;   // row-uniform (updates use row-reduced max)
    float l_p = 0.f;         // per-lane partial of l_i

#pragma unroll
    for (int i = 0; i < 4; ++i) gl_lds16(gK[i], &Ks[0][oK[i]]);
#pragma unroll
    for (int i = 0; i < 4; ++i) gl_lds16(gV[i], &Vst[0][oV[i]]);

    for (int kt = 0; kt <= qt; ++kt) {
      const int cur = kt & 1;
      const int kbase = kt * 64;
      if (kt < qt) {
        const long kb = (long)(kt + 1) * 64;
        const int nb = cur ^ 1;
#pragma unroll
        for (int i = 0; i < 4; ++i) gl_lds16(gK[i] + kb * D, &Ks[nb][oK[i]]);
#pragma unroll
        for (int i = 0; i < 4; ++i) gl_lds16(gV[i] + kb, &Vst[nb][oV[i]]);
        asm volatile("s_waitcnt vmcnt(8)" ::: "memory");
      } else {
        asm volatile("s_waitcnt vmcnt(0)" ::: "memory");
      }
      __builtin_amdgcn_s_barrier();   // B1: tile kt visible to all waves

      const unsigned short* Kb = &Ks[cur][0];
      const unsigned short* Vb = &Vst[cur][0];

      floatx4 sc[4];
#pragma unroll
      for (int nt = 0; nt < 4; ++nt) sc[nt] = (floatx4){0.f, 0.f, 0.f, 0.f};
      __builtin_amdgcn_s_setprio(1);
#pragma unroll
      for (int nt = 0; nt < 4; ++nt) {
        const int krow = nt * 16 + l16;
#pragma unroll
        for (int ks = 0; ks < 4; ++ks) {
          const int cp = (ks * 4 + quad) ^ lx7;
          short8 kf = *(const short8*)&Kb[krow * 128 + cp * 8];
          sc[nt] = __builtin_amdgcn_mfma_f32_16x16x32_bf16(kf, aq[ks], sc[nt], 0, 0, 0);
        }
      }
      __builtin_amdgcn_s_setprio(0);

      float sv[4][4];
      float lmax = -INFINITY;
      if (kt == qt) {
        const int kg0 = kbase + quad * 4;
#pragma unroll
        for (int nt = 0; nt < 4; ++nt)
#pragma unroll
          for (int rg = 0; rg < 4; ++rg) {
            float v = sc[nt][rg];
            if (kg0 + nt * 16 + rg > qrow) v = -INFINITY;
            sv[nt][rg] = v;
            lmax = fmaxf(lmax, v);
          }
      } else {
#pragma unroll
        for (int nt = 0; nt < 4; ++nt)
#pragma unroll
          for (int rg = 0; rg < 4; ++rg) {
            sv[nt][rg] = sc[nt][rg];
            lmax = fmaxf(lmax, sc[nt][rg]);
          }
      }

      float al = 1.0f;
      if (__any(lmax > m_i + 8.0f)) {
        float rmax = fmaxf(lmax, __shfl_xor(lmax, 16));
        rmax = fmaxf(rmax, __shfl_xor(rmax, 32));
        const float mn = fmaxf(m_i, rmax);
        al = exp2f(m_i - mn);
        m_i = mn;
#pragma unroll
        for (int t = 0; t < 8; ++t)
#pragma unroll
          for (int rg = 0; rg < 4; ++rg) o_acc[t][rg] *= al;
      }

      float rsum = 0.f;
#pragma unroll
      for (int nt = 0; nt < 4; ++nt) {
        float p0 = exp2f(sv[nt][0] - m_i), p1 = exp2f(sv[nt][1] - m_i);
        float p2 = exp2f(sv[nt][2] - m_i), p3 = exp2f(sv[nt][3] - m_i);
        rsum += (p0 + p1) + (p2 + p3);
        *(short4b*)&Ps[qloc * PS + nt * 16 + quad * 4] = pack4bf(p0, p1, p2, p3);
      }
      l_p = l_p * al + rsum;

      short8 pf[2];
#pragma unroll
      for (int ks = 0; ks < 2; ++ks)
        pf[ks] = *(const short8*)&Ps[qloc * PS + ks * 32 + quad * 8];

      __builtin_amdgcn_s_setprio(1);
#pragma unroll
      for (int t = 0; t < 8; ++t) {
        const int drow = t * 16 + l16;
#pragma unroll
        for (int ks = 0; ks < 2; ++ks) {
          const int cp = (ks * 4 + quad) ^ lx7;
          short8 vf = *(const short8*)&Vb[drow * 64 + cp * 8];
          o_acc[t] = __builtin_amdgcn_mfma_f32_16x16x32_bf16(vf, pf[ks], o_acc[t], 0, 0, 0);
        }
      }
      __builtin_amdgcn_s_setprio(0);
      __builtin_amdgcn_s_barrier();   // B2: all waves done reading buf cur
    }

    float l_i = l_p + __shfl_xor(l_p, 16);
    l_i += __shfl_xor(l_i, 32);
    const float rl = 1.0f / l_i;
    unsigned short* op = O + headoff + (long)qrow * D;
#pragma unroll
    for (int t = 0; t < 8; ++t) {
      *(short4b*)(op + t * 16 + quad * 4) =
          pack4bf(o_acc[t][0] * rl, o_acc[t][1] * rl, o_acc[t][2] * rl, o_acc[t][3] * rl);
    }
  }
}

extern "C" void kernel_launch(void* const* d_in, const int* in_sizes, int n_in,
                              void* d_out, int out_size, void* d_ws, size_t ws_size,
                              hipStream_t stream) {
  const float* query = (const float*)d_in[0];
  const float* key_  = (const float*)d_in[1];
  const float* value = (const float*)d_in[2];
  const float* Wq = (const float*)d_in[3];
  const float* bq = (const float*)d_in[4];
  const float* Wk = (const float*)d_in[5];
  const float* bk = (const float*)d_in[6];
  const float* Wv = (const float*)d_in[7];
  const float* bv = (const float*)d_in[8];
  const float* Wo = (const float*)d_in[9];
  const float* bo = (const float*)d_in[10];
  float* out = (float*)d_out;

  constexpr int Bz = 2, S = 2048, D = 2048;
  constexpr int M = Bz * S;
  constexpr long NELEM = (long)M * D;
  constexpr long WELEM = (long)D * D;

  const float qscale = 0.08838834764831845f * LOG2E;
  dim3 gridG(D / 128, M / 128);

  const size_t need_full = (size_t)(6 * NELEM + 4 * WELEM) * 2;

  if (ws_size >= need_full) {
    unsigned short* Qp  = (unsigned short*)d_ws;
    unsigned short* Kp  = Qp + NELEM;
    unsigned short* Vt  = Kp + NELEM;
    unsigned short* Xq  = Vt + NELEM;
    unsigned short* Xk  = Xq + NELEM;
    unsigned short* Xv  = Xk + NELEM;
    unsigned short* Wqb = Xv + NELEM;
    unsigned short* Wkb = Wqb + WELEM;
    unsigned short* Wvb = Wkb + WELEM;
    unsigned short* Wob = Wvb + WELEM;
    unsigned short* Oa  = Xq;

    cvt7_k<<<dim3(4096, 7), 256, 0, stream>>>(
        query, key_, value, Wq, Wk, Wv, Wo,
        Xq, Xk, Xv, Wqb, Wkb, Wvb, Wob, (int)NELEM, (int)WELEM);

    gemmqkv_k<<<dim3(16, 16, 3), 512, 0, stream>>>(
        Xq, Xk, Xv, Wqb, Wkb, Wvb, bq, bk, bv, Qp, Kp, Vt, qscale);

    flash_attn_k<<<dim3(16, 32), 256, 0, stream>>>(Qp, Kp, Vt, Oa);

    gemmo_k<<<dim3(16, 16), 512, 0, stream>>>(Oa, Wob, bo, out);
  } else {
    unsigned short* Qp = (unsigned short*)d_ws;
    unsigned short* Kp = Qp + NELEM;
    unsigned short* Vt = Kp + NELEM;
    unsigned short* Oa = Vt + NELEM;

    gemm_bias_k<false, true, false><<<gridG, 256, 0, stream>>>(query, Wq, bq, Qp, M, D, D, qscale);
    gemm_bias_k<false, true, false><<<gridG, 256, 0, stream>>>(key_,  Wk, bk, Kp, M, D, D, 1.0f);
    gemm_bias_k<false, true, true ><<<gridG, 256, 0, stream>>>(value, Wv, bv, Vt, M, D, D, 1.0f);

    flash_attn_k<<<dim3(16, 32), 256, 0, stream>>>(Qp, Kp, Vt, Oa);

    gemm_bias_k<true, false, false><<<gridG, 256, 0, stream>>>(Oa, Wo, bo, out, M, D, D, 1.0f);
  }
}